// Round 2
// baseline (8575.694 us; speedup 1.0000x reference)
//
#include <hip/hip_runtime.h>
#include <hip/hip_fp16.h>
#include <math.h>

#define WW 128
#define HH 128
#define DD 128
#define HW (WW * HH)
#define VOL (WW * HH * DD)

// ---- storage-type helpers (fp32 or fp16 scratch) ----
__device__ __forceinline__ float ldv(const float* p) { return *p; }
__device__ __forceinline__ float ldv(const __half* p) { return __half2float(*p); }
__device__ __forceinline__ void stv(float* p, float v) { *p = v; }
__device__ __forceinline__ void stv(__half* p, float v) { *p = __float2half(v); }

// Halo tile for an output tile of 1(d) x 2(h) x 128(w):
// 3 d-planes x 4 h-rows x 130 w columns, one channel at a time.
// sbuf row r = dd*4 + hh holds global (d0+dd-1, hb+hh-1); column ww holds gw = ww-1.
template <typename T>
__device__ __forceinline__ void load_halo(float (*sbuf)[130],
                                          const T* __restrict__ base,
                                          int d0, int hb)
{
    const int x = threadIdx.x;   // 0..127
    const int y = threadIdx.y;   // 0..1
#pragma unroll
    for (int r = y; r < 12; r += 2) {
        const int dd = r >> 2;   // 0..2
        const int hh = r & 3;    // 0..3
        const int gd = d0 + dd - 1;
        const int gh = hb + hh - 1;
        const bool ok = ((unsigned)gd < (unsigned)DD) && ((unsigned)gh < (unsigned)HH);
        const T* rowp = base + (size_t)gd * HW + (size_t)gh * WW;
        float v0 = 0.f;
        if (ok && x >= 1) v0 = ldv(rowp + (x - 1));
        sbuf[r][x] = v0;
        if (x < 2) {
            float v1 = 0.f;
            if (ok && (x + 127) < WW) v1 = ldv(rowp + (x + 127));
            sbuf[r][128 + x] = v1;
        }
    }
}

// Generic 3x3x3 conv, 8 input channels, OC output channels.
// wt layout: [OC][8][3][3][3]. If NORM: L1-normalize across OC per voxel.
template <int OC, bool RELU, bool NORM, typename TI, typename TO>
__global__ __launch_bounds__(256) void conv_k(const TI* __restrict__ in,
                                              const float* __restrict__ wt,
                                              const float* __restrict__ bias,
                                              TO* __restrict__ out)
{
    __shared__ float s[2][12][130];
    const int bid = blockIdx.x;
    const int d0 = bid >> 6;          // 128 d-slices
    const int hb = (bid & 63) << 1;   // 64 h-pairs
    const int x = threadIdx.x, y = threadIdx.y;
    const int h = hb + y;
    const int idx = d0 * HW + h * WW + x;

    float acc[OC];
#pragma unroll
    for (int o = 0; o < OC; ++o) acc[o] = bias ? bias[o] : 0.f;

    load_halo(s[0], in, d0, hb);
    __syncthreads();
#pragma unroll 1
    for (int c = 0; c < 8; ++c) {
        if (c + 1 < 8) load_halo(s[(c + 1) & 1], in + (size_t)(c + 1) * VOL, d0, hb);
        float (*sb)[130] = s[c & 1];
#pragma unroll
        for (int kd = 0; kd < 3; ++kd) {
#pragma unroll
            for (int kh = 0; kh < 3; ++kh) {
                const float v0 = sb[kd * 4 + y + kh][x];
                const float v1 = sb[kd * 4 + y + kh][x + 1];
                const float v2 = sb[kd * 4 + y + kh][x + 2];
                // thread-uniform weight indices -> scalar loads
                const float* wp = wt + (size_t)c * 27 + kd * 9 + kh * 3;
#pragma unroll
                for (int o = 0; o < OC; ++o) {
                    const float* w8 = wp + (size_t)o * (8 * 27);
                    acc[o] += v0 * w8[0] + v1 * w8[1] + v2 * w8[2];
                }
            }
        }
        if (c + 1 < 8) __syncthreads();
    }

    if (NORM) {
        float ssum = 0.f;
#pragma unroll
        for (int o = 0; o < OC; ++o) ssum += fabsf(acc[o]);
        const float inv = 1.0f / fmaxf(ssum, 1e-12f);
#pragma unroll
        for (int o = 0; o < OC; ++o) stv(out + (size_t)o * VOL + idx, acc[o] * inv);
    } else {
#pragma unroll
        for (int o = 0; o < OC; ++o) {
            float v = acc[o];
            if (RELU) v = fmaxf(v, 0.f);
            stv(out + (size_t)o * VOL + idx, v);
        }
    }
}

// Adaptive conv: out[c,p] = sum_k wn[k,p] * in[c, p+offset(k)], zero-padded.
template <int CH, typename TIN, typename TW, typename TOUT>
__global__ __launch_bounds__(256) void adapt_k(const TIN* __restrict__ in,
                                               const TW* __restrict__ wn,
                                               TOUT* __restrict__ out)
{
    __shared__ float s[2][12][130];
    const int bid = blockIdx.x;
    const int d0 = bid >> 6;
    const int hb = (bid & 63) << 1;
    const int x = threadIdx.x, y = threadIdx.y;
    const int h = hb + y;
    const int idx = d0 * HW + h * WW + x;

    float wk[27];
#pragma unroll
    for (int k = 0; k < 27; ++k) wk[k] = ldv(wn + (size_t)k * VOL + idx);

    load_halo(s[0], in, d0, hb);
    __syncthreads();
#pragma unroll 1
    for (int c = 0; c < CH; ++c) {
        if (c + 1 < CH) load_halo(s[(c + 1) & 1], in + (size_t)(c + 1) * VOL, d0, hb);
        float (*sb)[130] = s[c & 1];
        float a = 0.f;
#pragma unroll
        for (int kd = 0; kd < 3; ++kd)
#pragma unroll
            for (int kh = 0; kh < 3; ++kh)
#pragma unroll
                for (int kw = 0; kw < 3; ++kw)
                    a += wk[kd * 9 + kh * 3 + kw] * sb[kd * 4 + y + kh][x + kw];
        stv(out + (size_t)c * VOL + idx, a);
        if (c + 1 < CH) __syncthreads();
    }
}

// Whole pipeline on a 2-buffer schedule.
// TA = activation scratch type, TW = weight-field scratch type.
template <typename TA, typename TW>
static void run_all(const float* x,
                    const float* ac1_w1, const float* ac1_b1, const float* ac1_w2,
                    const float* ac2_w1, const float* ac2_b1, const float* ac2_w2,
                    const float* ac3_w1, const float* ac3_b1, const float* ac3_w2,
                    const float* mid_w, const float* mid_b,
                    const float* out_w, const float* out_b,
                    float* outp, void* d_ws, hipStream_t stream)
{
    const size_t V = (size_t)VOL;
    TW* Wb = (TW*)d_ws;
    TA* B1 = (TA*)((char*)d_ws + 27 * V * sizeof(TW));
    TA* B2 = B1 + 8 * V;
    TA* F0 = B1;          // block-3 single-channel ping-pong (B1 is free there)
    TA* F1 = B1 + V;

    dim3 grid(DD * (HH / 2));   // 8192 blocks
    dim3 blk(128, 2);

    // ---- adaptive block 1 (input x) ----
    conv_k<8, true, false><<<grid, blk, 0, stream>>>(x, ac1_w1, ac1_b1, B1);
    conv_k<27, false, true><<<grid, blk, 0, stream>>>(B1, ac1_w2, (const float*)nullptr, Wb);
    adapt_k<8><<<grid, blk, 0, stream>>>(x, Wb, B2);
    adapt_k<8><<<grid, blk, 0, stream>>>(B2, Wb, B1);
    adapt_k<8><<<grid, blk, 0, stream>>>(B1, Wb, B2);               // B2 = block1 out
    conv_k<8, false, false><<<grid, blk, 0, stream>>>(B2, mid_w, mid_b, B1);  // B1 = mid

    // ---- adaptive block 2 (input mid=B1) ----
    conv_k<8, true, false><<<grid, blk, 0, stream>>>(B1, ac2_w1, ac2_b1, B2);
    conv_k<27, false, true><<<grid, blk, 0, stream>>>(B2, ac2_w2, (const float*)nullptr, Wb);
    adapt_k<8><<<grid, blk, 0, stream>>>(B1, Wb, B2);
    adapt_k<8><<<grid, blk, 0, stream>>>(B2, Wb, B1);
    adapt_k<8><<<grid, blk, 0, stream>>>(B1, Wb, B2);               // B2 = mid2

    // ---- block 3: out conv + adaptive block (weights from mid2=B2) ----
    conv_k<8, true, false><<<grid, blk, 0, stream>>>(B2, ac3_w1, ac3_b1, B1);
    conv_k<27, false, true><<<grid, blk, 0, stream>>>(B1, ac3_w2, (const float*)nullptr, Wb);
    conv_k<1, false, false><<<grid, blk, 0, stream>>>(B2, out_w, out_b, F0); // B1 free now
    adapt_k<1><<<grid, blk, 0, stream>>>(F0, Wb, F1);
    adapt_k<1><<<grid, blk, 0, stream>>>(F1, Wb, F0);
    adapt_k<1><<<grid, blk, 0, stream>>>(F0, Wb, outp);
}

extern "C" void kernel_launch(void* const* d_in, const int* in_sizes, int n_in,
                              void* d_out, int out_size, void* d_ws, size_t ws_size,
                              hipStream_t stream)
{
    (void)in_sizes; (void)n_in; (void)out_size;

    const float* x      = (const float*)d_in[0];
    const float* ac1_w1 = (const float*)d_in[1];
    const float* ac1_b1 = (const float*)d_in[2];
    const float* ac1_w2 = (const float*)d_in[3];
    const float* ac2_w1 = (const float*)d_in[4];
    const float* ac2_b1 = (const float*)d_in[5];
    const float* ac2_w2 = (const float*)d_in[6];
    const float* ac3_w1 = (const float*)d_in[7];
    const float* ac3_b1 = (const float*)d_in[8];
    const float* ac3_w2 = (const float*)d_in[9];
    const float* mid_w  = (const float*)d_in[10];
    const float* mid_b  = (const float*)d_in[11];
    const float* out_w  = (const float*)d_in[12];
    const float* out_b  = (const float*)d_in[13];
    float* outp = (float*)d_out;

    const size_t V = (size_t)VOL;
    const size_t need_f32f32 = (27 * 4 + 16 * 4) * V;   // ~344 MiB
    const size_t need_f32h   = (27 * 2 + 16 * 4) * V;   // ~236 MiB
    // tier 3 (all-fp16) needs (27*2 + 16*2)*V ~ 172 MiB

    if (ws_size >= need_f32f32) {
        run_all<float, float>(x, ac1_w1, ac1_b1, ac1_w2, ac2_w1, ac2_b1, ac2_w2,
                              ac3_w1, ac3_b1, ac3_w2, mid_w, mid_b, out_w, out_b,
                              outp, d_ws, stream);
    } else if (ws_size >= need_f32h) {
        run_all<float, __half>(x, ac1_w1, ac1_b1, ac1_w2, ac2_w1, ac2_b1, ac2_w2,
                               ac3_w1, ac3_b1, ac3_w2, mid_w, mid_b, out_w, out_b,
                               outp, d_ws, stream);
    } else {
        run_all<__half, __half>(x, ac1_w1, ac1_b1, ac1_w2, ac2_w1, ac2_b1, ac2_w2,
                                ac3_w1, ac3_b1, ac3_w2, mid_w, mid_b, out_w, out_b,
                                outp, d_ws, stream);
    }
}

// Round 3
// 1582.703 us; speedup vs baseline: 5.4184x; 5.4184x over previous
//
#include <hip/hip_runtime.h>
#include <hip/hip_fp16.h>
#include <math.h>

#define WW 128
#define HH 128
#define DD 128
#define HW (WW * HH)
#define VOL (WW * HH * DD)

typedef _Float16 f16x8 __attribute__((ext_vector_type(8)));
typedef float f32x4 __attribute__((ext_vector_type(4)));

// ---- storage-type helpers (fp32 or fp16) ----
__device__ __forceinline__ float ldv(const float* p) { return *p; }
__device__ __forceinline__ float ldv(const _Float16* p) { return (float)*p; }
__device__ __forceinline__ void stv(float* p, float v) { *p = v; }
__device__ __forceinline__ void stv(_Float16* p, float v) { *p = (_Float16)v; }

// ==========================================================================
// Implicit-GEMM 3x3x3 conv, 8 in-channels, OC out-channels, via MFMA f16.
//   GEMM view: D[OC, voxels] = W[OC, K=216] * im2col[K, voxels]
//   K order: k = tap*8 + c  ->  a lane's 8-k B-fragment = 8 channels of ONE
//   tap site = one ds_read_b128 from the channel-interleaved fp16 halo.
// Block tile: 4d x 4h x 64w (2048 voxels), wave wid owns d-slice wid.
// Halo: 6 x 6 x 66 sites x 8ch fp16 = 38,016 B LDS.
// ==========================================================================
template <typename TI>
__device__ __forceinline__ void stage_halo(f16x8* hal, const TI* __restrict__ in,
                                           int d0, int h0, int w0)
{
    const int tid = threadIdx.x;
    for (int s = tid; s < 6 * 6 * 66; s += 256) {
        const int dd = s / (6 * 66);
        const int r  = s % (6 * 66);
        const int hh = r / 66;
        const int ww = r % 66;
        const int gd = d0 + dd - 1, gh = h0 + hh - 1, gw = w0 + ww - 1;
        f16x8 v = {};
        if ((unsigned)gd < (unsigned)DD && (unsigned)gh < (unsigned)HH &&
            (unsigned)gw < (unsigned)WW) {
            const size_t base = (size_t)gd * HW + (size_t)gh * WW + gw;
#pragma unroll
            for (int c = 0; c < 8; ++c)
                v[c] = (_Float16)ldv(in + (size_t)c * VOL + base);
        }
        hal[s] = v;
    }
}

template <int OC, bool RELU, bool NORM, typename TI, typename TO>
__global__ __launch_bounds__(256) void conv_mfma(const TI* __restrict__ in,
                                                 const float* __restrict__ wt,
                                                 const float* __restrict__ bias,
                                                 TO* __restrict__ out)
{
    __shared__ f16x8 hal[6 * 6 * 66];

    const int bid  = blockIdx.x;           // 2048 blocks: 32d x 32h x 2w
    const int wblk = bid & 1;
    const int hblk = (bid >> 1) & 31;
    const int dblk = bid >> 6;
    const int d0 = dblk * 4, h0 = hblk * 4, w0 = wblk * 64;

    stage_halo(hal, in, d0, h0, w0);

    const int tid  = threadIdx.x;
    const int lane = tid & 63;
    const int wid  = tid >> 6;             // wave id = local d slice
    const int n    = lane & 15;            // A: m=lane&15; B: n=lane&15; C: col
    const int quad = lane >> 4;

    // ---- A fragments: all weights resident in VGPRs, loaded once ----
    constexpr int MT = (OC > 16) ? 2 : 1;  // m-tiles of 16 rows
    f16x8 afr[MT][7];
#pragma unroll
    for (int s = 0; s < 7; ++s) {
        const int tap = s * 4 + quad;      // k = tap*8 + c; lane covers c=0..7
#pragma unroll
        for (int mt = 0; mt < MT; ++mt) {
            const int m = mt * 16 + n;
            f16x8 a = {};
            if (tap < 27 && m < OC) {
#pragma unroll
                for (int j = 0; j < 8; ++j)       // j = channel c
                    a[j] = (_Float16)wt[(size_t)m * 216 + (size_t)j * 27 + tap];
            }
            afr[mt][s] = a;
        }
    }

    // ---- B site offsets per k-step (tap -> kd,kh,kw), clamped for pad tap ----
    int boff[7];
#pragma unroll
    for (int s = 0; s < 7; ++s) {
        int tap = s * 4 + quad;
        if (tap > 26) tap = 26;            // A is zero there; any valid addr ok
        const int kd = tap / 9, kh = (tap % 9) / 3, kw = tap % 3;
        boff[s] = (wid + kd) * (6 * 66) + kh * 66 + kw + n;
    }

    // ---- bias (per accumulator row), zero for NORM path ----
    float bv[MT][4];
#pragma unroll
    for (int mt = 0; mt < MT; ++mt)
#pragma unroll
        for (int r = 0; r < 4; ++r) {
            const int o = mt * 16 + quad * 4 + r;
            bv[mt][r] = (!NORM && bias != nullptr && o < OC) ? bias[o] : 0.f;
        }

    __syncthreads();

    const size_t outbase = (size_t)(d0 + wid) * HW + (size_t)h0 * WW + w0;

#pragma unroll 1
    for (int nt = 0; nt < 16; ++nt) {      // 16 n-tiles of 16 voxels per wave
        const int hl = nt >> 2, wseg = nt & 3;
        const int add = hl * 66 + wseg * 16;
        f32x4 acc[MT];
#pragma unroll
        for (int mt = 0; mt < MT; ++mt) {
            acc[mt][0] = bv[mt][0]; acc[mt][1] = bv[mt][1];
            acc[mt][2] = bv[mt][2]; acc[mt][3] = bv[mt][3];
        }
#pragma unroll
        for (int s = 0; s < 7; ++s) {
            const f16x8 b = hal[boff[s] + add];
            acc[0] = __builtin_amdgcn_mfma_f32_16x16x32_f16(afr[0][s], b, acc[0], 0, 0, 0);
            if (MT > 1)
                acc[1] = __builtin_amdgcn_mfma_f32_16x16x32_f16(afr[1][s], b, acc[1], 0, 0, 0);
        }
        const size_t idx = outbase + (size_t)hl * WW + wseg * 16 + n;
        if (NORM) {
            float ssum = 0.f;
#pragma unroll
            for (int mt = 0; mt < MT; ++mt)
#pragma unroll
                for (int r = 0; r < 4; ++r) ssum += fabsf(acc[mt][r]);
            ssum += __shfl_xor(ssum, 16);
            ssum += __shfl_xor(ssum, 32);
            const float inv = 1.0f / fmaxf(ssum, 1e-12f);
#pragma unroll
            for (int mt = 0; mt < MT; ++mt)
#pragma unroll
                for (int r = 0; r < 4; ++r) {
                    const int o = mt * 16 + quad * 4 + r;
                    if (o < OC) stv(out + (size_t)o * VOL + idx, acc[mt][r] * inv);
                }
        } else {
#pragma unroll
            for (int mt = 0; mt < MT; ++mt)
#pragma unroll
                for (int r = 0; r < 4; ++r) {
                    const int o = mt * 16 + quad * 4 + r;
                    float v = acc[mt][r];
                    if (RELU) v = fmaxf(v, 0.f);
                    if (o < OC) stv(out + (size_t)o * VOL + idx, v);
                }
        }
    }
}

// ==========================================================================
// Adaptive conv (per-voxel 27-tap weights, shared across channels) — VALU,
// memory-bound. Halo tile 1d x 2h x 128w per block, fp32 LDS.
// ==========================================================================
template <typename T>
__device__ __forceinline__ void load_halo(float (*sbuf)[130],
                                          const T* __restrict__ base,
                                          int d0, int hb)
{
    const int x = threadIdx.x;
    const int y = threadIdx.y;
#pragma unroll
    for (int r = y; r < 12; r += 2) {
        const int dd = r >> 2;
        const int hh = r & 3;
        const int gd = d0 + dd - 1;
        const int gh = hb + hh - 1;
        const bool ok = ((unsigned)gd < (unsigned)DD) && ((unsigned)gh < (unsigned)HH);
        const T* rowp = base + (size_t)gd * HW + (size_t)gh * WW;
        float v0 = 0.f;
        if (ok && x >= 1) v0 = ldv(rowp + (x - 1));
        sbuf[r][x] = v0;
        if (x < 2) {
            float v1 = 0.f;
            if (ok && (x + 127) < WW) v1 = ldv(rowp + (x + 127));
            sbuf[r][128 + x] = v1;
        }
    }
}

template <int CH, typename TIN, typename TW, typename TOUT>
__global__ __launch_bounds__(256) void adapt_k(const TIN* __restrict__ in,
                                               const TW* __restrict__ wn,
                                               TOUT* __restrict__ out)
{
    __shared__ float s[2][12][130];
    const int bid = blockIdx.x;
    const int d0 = bid >> 6;
    const int hb = (bid & 63) << 1;
    const int x = threadIdx.x, y = threadIdx.y;
    const int h = hb + y;
    const int idx = d0 * HW + h * WW + x;

    float wk[27];
#pragma unroll
    for (int k = 0; k < 27; ++k) wk[k] = ldv(wn + (size_t)k * VOL + idx);

    load_halo(s[0], in, d0, hb);
    __syncthreads();
#pragma unroll 1
    for (int c = 0; c < CH; ++c) {
        if (c + 1 < CH) load_halo(s[(c + 1) & 1], in + (size_t)(c + 1) * VOL, d0, hb);
        float (*sb)[130] = s[c & 1];
        float a = 0.f;
#pragma unroll
        for (int kd = 0; kd < 3; ++kd)
#pragma unroll
            for (int kh = 0; kh < 3; ++kh)
#pragma unroll
                for (int kw = 0; kw < 3; ++kw)
                    a += wk[kd * 9 + kh * 3 + kw] * sb[kd * 4 + y + kh][x + kw];
        stv(out + (size_t)c * VOL + idx, a);
        if (c + 1 < CH) __syncthreads();
    }
}

extern "C" void kernel_launch(void* const* d_in, const int* in_sizes, int n_in,
                              void* d_out, int out_size, void* d_ws, size_t ws_size,
                              hipStream_t stream)
{
    (void)in_sizes; (void)n_in; (void)out_size; (void)ws_size;

    const float* x      = (const float*)d_in[0];
    const float* ac1_w1 = (const float*)d_in[1];
    const float* ac1_b1 = (const float*)d_in[2];
    const float* ac1_w2 = (const float*)d_in[3];
    const float* ac2_w1 = (const float*)d_in[4];
    const float* ac2_b1 = (const float*)d_in[5];
    const float* ac2_w2 = (const float*)d_in[6];
    const float* ac3_w1 = (const float*)d_in[7];
    const float* ac3_b1 = (const float*)d_in[8];
    const float* ac3_w2 = (const float*)d_in[9];
    const float* mid_w  = (const float*)d_in[10];
    const float* mid_b  = (const float*)d_in[11];
    const float* out_w  = (const float*)d_in[12];
    const float* out_b  = (const float*)d_in[13];
    float* outp = (float*)d_out;

    // fp16 scratch: Wb[27V] | B1[8V] | B2[8V]  (F0/F1 alias B1's space)
    const size_t V = (size_t)VOL;
    _Float16* Wb = (_Float16*)d_ws;
    _Float16* B1 = Wb + 27 * V;
    _Float16* B2 = B1 + 8 * V;
    _Float16* F0 = B1;
    _Float16* F1 = B1 + V;

    const dim3 cgrid(2048), cblk(256);      // conv_mfma
    const dim3 agrid(DD * (HH / 2)), ablk(128, 2);  // adapt_k

    // ---- adaptive block 1 (input x) ----
    conv_mfma<8, true, false, float, _Float16><<<cgrid, cblk, 0, stream>>>(x, ac1_w1, ac1_b1, B1);
    conv_mfma<27, false, true, _Float16, _Float16><<<cgrid, cblk, 0, stream>>>(B1, ac1_w2, nullptr, Wb);
    adapt_k<8, float, _Float16, _Float16><<<agrid, ablk, 0, stream>>>(x, Wb, B2);
    adapt_k<8, _Float16, _Float16, _Float16><<<agrid, ablk, 0, stream>>>(B2, Wb, B1);
    adapt_k<8, _Float16, _Float16, _Float16><<<agrid, ablk, 0, stream>>>(B1, Wb, B2);  // B2 = block1 out
    conv_mfma<8, false, false, _Float16, _Float16><<<cgrid, cblk, 0, stream>>>(B2, mid_w, mid_b, B1);  // B1 = mid

    // ---- adaptive block 2 (input mid = B1) ----
    conv_mfma<8, true, false, _Float16, _Float16><<<cgrid, cblk, 0, stream>>>(B1, ac2_w1, ac2_b1, B2);
    conv_mfma<27, false, true, _Float16, _Float16><<<cgrid, cblk, 0, stream>>>(B2, ac2_w2, nullptr, Wb);
    adapt_k<8, _Float16, _Float16, _Float16><<<agrid, ablk, 0, stream>>>(B1, Wb, B2);
    adapt_k<8, _Float16, _Float16, _Float16><<<agrid, ablk, 0, stream>>>(B2, Wb, B1);
    adapt_k<8, _Float16, _Float16, _Float16><<<agrid, ablk, 0, stream>>>(B1, Wb, B2);  // B2 = mid2

    // ---- block 3: out conv + adaptive block (weights from mid2 = B2) ----
    conv_mfma<8, true, false, _Float16, _Float16><<<cgrid, cblk, 0, stream>>>(B2, ac3_w1, ac3_b1, B1);
    conv_mfma<27, false, true, _Float16, _Float16><<<cgrid, cblk, 0, stream>>>(B1, ac3_w2, nullptr, Wb);
    conv_mfma<1, false, false, _Float16, _Float16><<<cgrid, cblk, 0, stream>>>(B2, out_w, out_b, F0);
    adapt_k<1, _Float16, _Float16, _Float16><<<agrid, ablk, 0, stream>>>(F0, Wb, F1);
    adapt_k<1, _Float16, _Float16, _Float16><<<agrid, ablk, 0, stream>>>(F1, Wb, F0);
    adapt_k<1, _Float16, _Float16, float><<<agrid, ablk, 0, stream>>>(F0, Wb, outp);
}

// Round 4
// 1573.871 us; speedup vs baseline: 5.4488x; 1.0056x over previous
//
#include <hip/hip_runtime.h>
#include <hip/hip_fp16.h>
#include <math.h>

#define WW 128
#define HH 128
#define DD 128
#define HW (WW * HH)
#define VOL (WW * HH * DD)

typedef _Float16 f16x8 __attribute__((ext_vector_type(8)));
typedef _Float16 f16x4 __attribute__((ext_vector_type(4)));
typedef float f32x4 __attribute__((ext_vector_type(4)));

// ---- storage-type helpers (fp32 or fp16) ----
__device__ __forceinline__ float ldv(const float* p) { return *p; }
__device__ __forceinline__ float ldv(const _Float16* p) { return (float)*p; }
__device__ __forceinline__ void stv(float* p, float v) { *p = v; }
__device__ __forceinline__ void stv(_Float16* p, float v) { *p = (_Float16)v; }

// ==========================================================================
// Implicit-GEMM 3x3x3 conv, 8 in-channels, OC out-channels, via MFMA f16.
//   GEMM view: D[OC, voxels] = W[OC, K=216] * im2col[K, voxels]
//   K order: k = tap*8 + c  ->  a lane's 8-k B-fragment = 8 channels of ONE
//   tap site = one ds_read_b128 from the channel-interleaved fp16 halo.
// Block tile: 4d x 4h x 64w (2048 voxels), wave wid owns d-slice wid.
// ==========================================================================
template <typename TI>
__device__ __forceinline__ void stage_halo(f16x8* hal, const TI* __restrict__ in,
                                           int d0, int h0, int w0)
{
    const int tid = threadIdx.x;
    for (int s = tid; s < 6 * 6 * 66; s += 256) {
        const int dd = s / (6 * 66);
        const int r  = s % (6 * 66);
        const int hh = r / 66;
        const int ww = r % 66;
        const int gd = d0 + dd - 1, gh = h0 + hh - 1, gw = w0 + ww - 1;
        f16x8 v = {};
        if ((unsigned)gd < (unsigned)DD && (unsigned)gh < (unsigned)HH &&
            (unsigned)gw < (unsigned)WW) {
            const size_t base = (size_t)gd * HW + (size_t)gh * WW + gw;
#pragma unroll
            for (int c = 0; c < 8; ++c)
                v[c] = (_Float16)ldv(in + (size_t)c * VOL + base);
        }
        hal[s] = v;
    }
}

template <int OC, bool RELU, bool NORM, typename TI, typename TO>
__global__ __launch_bounds__(256) void conv_mfma(const TI* __restrict__ in,
                                                 const float* __restrict__ wt,
                                                 const float* __restrict__ bias,
                                                 TO* __restrict__ out)
{
    __shared__ f16x8 hal[6 * 6 * 66];

    const int bid  = blockIdx.x;           // 2048 blocks: 32d x 32h x 2w
    const int wblk = bid & 1;
    const int hblk = (bid >> 1) & 31;
    const int dblk = bid >> 6;
    const int d0 = dblk * 4, h0 = hblk * 4, w0 = wblk * 64;

    stage_halo(hal, in, d0, h0, w0);

    const int tid  = threadIdx.x;
    const int lane = tid & 63;
    const int wid  = tid >> 6;             // wave id = local d slice
    const int n    = lane & 15;
    const int quad = lane >> 4;

    // ---- A fragments: all weights resident in VGPRs, loaded once ----
    constexpr int MT = (OC > 16) ? 2 : 1;  // m-tiles of 16 rows
    f16x8 afr[MT][7];
#pragma unroll
    for (int s = 0; s < 7; ++s) {
        const int tap = s * 4 + quad;      // k = tap*8 + c
#pragma unroll
        for (int mt = 0; mt < MT; ++mt) {
            const int m = mt * 16 + n;
            f16x8 a = {};
            if (tap < 27 && m < OC) {
#pragma unroll
                for (int j = 0; j < 8; ++j)       // j = channel c
                    a[j] = (_Float16)wt[(size_t)m * 216 + (size_t)j * 27 + tap];
            }
            afr[mt][s] = a;
        }
    }

    // ---- B site offsets per k-step ----
    int boff[7];
#pragma unroll
    for (int s = 0; s < 7; ++s) {
        int tap = s * 4 + quad;
        if (tap > 26) tap = 26;            // A is zero there
        const int kd = tap / 9, kh = (tap % 9) / 3, kw = tap % 3;
        boff[s] = (wid + kd) * (6 * 66) + kh * 66 + kw + n;
    }

    float bv[MT][4];
#pragma unroll
    for (int mt = 0; mt < MT; ++mt)
#pragma unroll
        for (int r = 0; r < 4; ++r) {
            const int o = mt * 16 + quad * 4 + r;
            bv[mt][r] = (!NORM && bias != nullptr && o < OC) ? bias[o] : 0.f;
        }

    __syncthreads();

    const size_t outbase = (size_t)(d0 + wid) * HW + (size_t)h0 * WW + w0;

#pragma unroll 1
    for (int nt = 0; nt < 16; ++nt) {      // 16 n-tiles of 16 voxels per wave
        const int hl = nt >> 2, wseg = nt & 3;
        const int add = hl * 66 + wseg * 16;
        f32x4 acc[MT];
#pragma unroll
        for (int mt = 0; mt < MT; ++mt) {
            acc[mt][0] = bv[mt][0]; acc[mt][1] = bv[mt][1];
            acc[mt][2] = bv[mt][2]; acc[mt][3] = bv[mt][3];
        }
#pragma unroll
        for (int s = 0; s < 7; ++s) {
            const f16x8 b = hal[boff[s] + add];
            acc[0] = __builtin_amdgcn_mfma_f32_16x16x32_f16(afr[0][s], b, acc[0], 0, 0, 0);
            if (MT > 1)
                acc[1] = __builtin_amdgcn_mfma_f32_16x16x32_f16(afr[1][s], b, acc[1], 0, 0, 0);
        }
        const size_t idx = outbase + (size_t)hl * WW + wseg * 16 + n;
        if (NORM) {
            float ssum = 0.f;
#pragma unroll
            for (int mt = 0; mt < MT; ++mt)
#pragma unroll
                for (int r = 0; r < 4; ++r) ssum += fabsf(acc[mt][r]);
            ssum += __shfl_xor(ssum, 16);
            ssum += __shfl_xor(ssum, 32);
            const float inv = 1.0f / fmaxf(ssum, 1e-12f);
#pragma unroll
            for (int mt = 0; mt < MT; ++mt)
#pragma unroll
                for (int r = 0; r < 4; ++r) {
                    const int o = mt * 16 + quad * 4 + r;
                    if (o < OC) stv(out + (size_t)o * VOL + idx, acc[mt][r] * inv);
                }
        } else {
#pragma unroll
            for (int mt = 0; mt < MT; ++mt)
#pragma unroll
                for (int r = 0; r < 4; ++r) {
                    const int o = mt * 16 + quad * 4 + r;
                    float v = acc[mt][r];
                    if (RELU) v = fmaxf(v, 0.f);
                    if (o < OC) stv(out + (size_t)o * VOL + idx, v);
                }
        }
    }
}

// ==========================================================================
// Adaptive conv v3: per-voxel 27-tap weights shared across channels.
// Thread = 4 consecutive w voxels. No LDS, no syncthreads. Weights live in
// registers as f16x4 (27 taps, loaded once, coalesced 512B/wave/tap).
// Input halo read straight from global (L1/L2 absorb the 9x re-reads).
// FMA via (float)f16 * (float)x -> v_fma_mix_f32, fp32 accumulate.
// ==========================================================================
template <int CH, typename TIN, typename TOUT>
__global__ __launch_bounds__(256) void adapt_v3(const TIN* __restrict__ in,
                                                const _Float16* __restrict__ wn,
                                                TOUT* __restrict__ out)
{
    const int tid = threadIdx.x;           // 256 threads
    const int wg  = tid & 31;              // 32 w-groups of 4
    const int hl  = tid >> 5;              // 0..7
    const int bid = blockIdx.x;            // 2048 = 128 d * 16 h-blocks
    const int d   = bid >> 4;
    const int h   = ((bid & 15) << 3) + hl;
    const int w0  = wg << 2;
    const size_t base = (size_t)d * HW + (size_t)h * WW + w0;

    // per-voxel weights: 27 taps x 4 voxels, fp16 in regs
    f16x4 wk[27];
#pragma unroll
    for (int k = 0; k < 27; ++k)
        wk[k] = *(const f16x4*)(wn + (size_t)k * VOL + base);

#pragma unroll 1
    for (int c = 0; c < CH; ++c) {
        const TIN* inc = in + (size_t)c * VOL;
        float acc[4] = {0.f, 0.f, 0.f, 0.f};
#pragma unroll
        for (int kd = 0; kd < 3; ++kd) {
            const int gd = d + kd - 1;
#pragma unroll
            for (int kh = 0; kh < 3; ++kh) {
                const int gh = h + kh - 1;
                const bool rowok = ((unsigned)gd < (unsigned)DD) &&
                                   ((unsigned)gh < (unsigned)HH);
                const TIN* rp = inc + (size_t)gd * HW + (size_t)gh * WW;
                float xv[6];   // input at w0-1 .. w0+4
                if (rowok) {
                    typedef TIN tin4 __attribute__((ext_vector_type(4)));
                    tin4 cen = *(const tin4*)(rp + w0);
                    xv[1] = (float)cen[0]; xv[2] = (float)cen[1];
                    xv[3] = (float)cen[2]; xv[4] = (float)cen[3];
                    xv[0] = (w0 > 0)   ? (float)rp[w0 - 1] : 0.f;
                    xv[5] = (w0 < 124) ? (float)rp[w0 + 4] : 0.f;
                } else {
#pragma unroll
                    for (int j = 0; j < 6; ++j) xv[j] = 0.f;
                }
                const int kb = kd * 9 + kh * 3;
#pragma unroll
                for (int kw = 0; kw < 3; ++kw) {
                    const f16x4 w4 = wk[kb + kw];
                    acc[0] += (float)w4[0] * xv[kw + 0];
                    acc[1] += (float)w4[1] * xv[kw + 1];
                    acc[2] += (float)w4[2] * xv[kw + 2];
                    acc[3] += (float)w4[3] * xv[kw + 3];
                }
            }
        }
        TOUT* op = out + (size_t)c * VOL + base;
        typedef TOUT tout4 __attribute__((ext_vector_type(4)));
        tout4 o4;
        o4[0] = (TOUT)acc[0]; o4[1] = (TOUT)acc[1];
        o4[2] = (TOUT)acc[2]; o4[3] = (TOUT)acc[3];
        *(tout4*)op = o4;
    }
}

extern "C" void kernel_launch(void* const* d_in, const int* in_sizes, int n_in,
                              void* d_out, int out_size, void* d_ws, size_t ws_size,
                              hipStream_t stream)
{
    (void)in_sizes; (void)n_in; (void)out_size; (void)ws_size;

    const float* x      = (const float*)d_in[0];
    const float* ac1_w1 = (const float*)d_in[1];
    const float* ac1_b1 = (const float*)d_in[2];
    const float* ac1_w2 = (const float*)d_in[3];
    const float* ac2_w1 = (const float*)d_in[4];
    const float* ac2_b1 = (const float*)d_in[5];
    const float* ac2_w2 = (const float*)d_in[6];
    const float* ac3_w1 = (const float*)d_in[7];
    const float* ac3_b1 = (const float*)d_in[8];
    const float* ac3_w2 = (const float*)d_in[9];
    const float* mid_w  = (const float*)d_in[10];
    const float* mid_b  = (const float*)d_in[11];
    const float* out_w  = (const float*)d_in[12];
    const float* out_b  = (const float*)d_in[13];
    float* outp = (float*)d_out;

    // fp16 scratch: Wb[27V] | B1[8V] | B2[8V]  (F0/F1 alias B1's space)
    const size_t V = (size_t)VOL;
    _Float16* Wb = (_Float16*)d_ws;
    _Float16* B1 = Wb + 27 * V;
    _Float16* B2 = B1 + 8 * V;
    _Float16* F0 = B1;
    _Float16* F1 = B1 + V;

    const dim3 cgrid(2048), cblk(256);      // conv_mfma
    const dim3 agrid(2048), ablk(256);      // adapt_v3

    // ---- adaptive block 1 (input x) ----
    conv_mfma<8, true, false, float, _Float16><<<cgrid, cblk, 0, stream>>>(x, ac1_w1, ac1_b1, B1);
    conv_mfma<27, false, true, _Float16, _Float16><<<cgrid, cblk, 0, stream>>>(B1, ac1_w2, nullptr, Wb);
    adapt_v3<8, float, _Float16><<<agrid, ablk, 0, stream>>>(x, Wb, B2);
    adapt_v3<8, _Float16, _Float16><<<agrid, ablk, 0, stream>>>(B2, Wb, B1);
    adapt_v3<8, _Float16, _Float16><<<agrid, ablk, 0, stream>>>(B1, Wb, B2);  // B2 = block1 out
    conv_mfma<8, false, false, _Float16, _Float16><<<cgrid, cblk, 0, stream>>>(B2, mid_w, mid_b, B1); // B1 = mid

    // ---- adaptive block 2 (input mid = B1) ----
    conv_mfma<8, true, false, _Float16, _Float16><<<cgrid, cblk, 0, stream>>>(B1, ac2_w1, ac2_b1, B2);
    conv_mfma<27, false, true, _Float16, _Float16><<<cgrid, cblk, 0, stream>>>(B2, ac2_w2, nullptr, Wb);
    adapt_v3<8, _Float16, _Float16><<<agrid, ablk, 0, stream>>>(B1, Wb, B2);
    adapt_v3<8, _Float16, _Float16><<<agrid, ablk, 0, stream>>>(B2, Wb, B1);
    adapt_v3<8, _Float16, _Float16><<<agrid, ablk, 0, stream>>>(B1, Wb, B2);  // B2 = mid2

    // ---- block 3: out conv + adaptive block (weights from mid2 = B2) ----
    conv_mfma<8, true, false, _Float16, _Float16><<<cgrid, cblk, 0, stream>>>(B2, ac3_w1, ac3_b1, B1);
    conv_mfma<27, false, true, _Float16, _Float16><<<cgrid, cblk, 0, stream>>>(B1, ac3_w2, nullptr, Wb);
    conv_mfma<1, false, false, _Float16, _Float16><<<cgrid, cblk, 0, stream>>>(B2, out_w, out_b, F0);
    adapt_v3<1, _Float16, _Float16><<<agrid, ablk, 0, stream>>>(F0, Wb, F1);
    adapt_v3<1, _Float16, _Float16><<<agrid, ablk, 0, stream>>>(F1, Wb, F0);
    adapt_v3<1, _Float16, float><<<agrid, ablk, 0, stream>>>(F0, Wb, outp);
}

// Round 5
// 1038.127 us; speedup vs baseline: 8.2607x; 1.5161x over previous
//
#include <hip/hip_runtime.h>
#include <hip/hip_fp16.h>
#include <math.h>

#define WW 128
#define HH 128
#define DD 128
#define HW (WW * HH)
#define VOL (WW * HH * DD)

typedef _Float16 f16x8 __attribute__((ext_vector_type(8)));
typedef _Float16 f16x4 __attribute__((ext_vector_type(4)));
typedef float f32x4 __attribute__((ext_vector_type(4)));

// ---- storage-type helpers ----
__device__ __forceinline__ float ldv(const float* p) { return *p; }
__device__ __forceinline__ float ldv(const _Float16* p) { return (float)*p; }
__device__ __forceinline__ void stv(float* p, float v) { *p = v; }
__device__ __forceinline__ void stv(_Float16* p, float v) { *p = (_Float16)v; }

// ==========================================================================
// cvt_x: planar fp32 (8ch) -> channel-interleaved f16x8 [d][h][w][c8]
// ==========================================================================
__global__ __launch_bounds__(256) void cvt_x(const float* __restrict__ x,
                                             _Float16* __restrict__ xi)
{
    const size_t v = (size_t)blockIdx.x * 256 + threadIdx.x;
    f16x8 o;
#pragma unroll
    for (int c = 0; c < 8; ++c) o[c] = (_Float16)x[(size_t)c * VOL + v];
    *(f16x8*)(xi + v * 8) = o;
}

// ==========================================================================
// Implicit-GEMM 3x3x3 conv via MFMA f16, input channel-interleaved f16x8.
//   D[OC, vox] = W[OC, K=216] * im2col[K, vox], K order k = tap*8 + c.
// Block tile 4d x 4h x 64w; halo 6x6x66 sites, ONE f16x8 load per site.
// OM: 0 = interleaved 8-ch out, 1 = planar 27-ch L1-normalized, 2 = planar 1-ch.
// ==========================================================================
template <int OC, bool RELU, int OM, typename TO>
__global__ __launch_bounds__(256) void conv_mfma(const _Float16* __restrict__ in,
                                                 const float* __restrict__ wt,
                                                 const float* __restrict__ bias,
                                                 TO* __restrict__ out)
{
    __shared__ f16x8 hal[6 * 6 * 66];

    const int bid  = blockIdx.x;           // 2048 blocks: 32d x 32h x 2w
    const int wblk = bid & 1;
    const int hblk = (bid >> 1) & 31;
    const int dblk = bid >> 6;
    const int d0 = dblk * 4, h0 = hblk * 4, w0 = wblk * 64;

    const int tid = threadIdx.x;
    for (int s = tid; s < 6 * 6 * 66; s += 256) {
        const int dd = s / (6 * 66);
        const int r  = s % (6 * 66);
        const int hh = r / 66;
        const int ww = r % 66;
        const int gd = d0 + dd - 1, gh = h0 + hh - 1, gw = w0 + ww - 1;
        f16x8 v = {};
        if ((unsigned)gd < (unsigned)DD && (unsigned)gh < (unsigned)HH &&
            (unsigned)gw < (unsigned)WW)
            v = *(const f16x8*)(in + ((size_t)gd * HW + (size_t)gh * WW + gw) * 8);
        hal[s] = v;
    }

    const int lane = tid & 63;
    const int wid  = tid >> 6;             // wave id = local d slice
    const int n    = lane & 15;
    const int quad = lane >> 4;

    // ---- A fragments: weights resident in VGPRs ----
    constexpr int MT = (OC > 16) ? 2 : 1;
    f16x8 afr[MT][7];
#pragma unroll
    for (int s = 0; s < 7; ++s) {
        const int tap = s * 4 + quad;      // k = tap*8 + c
#pragma unroll
        for (int mt = 0; mt < MT; ++mt) {
            const int m = mt * 16 + n;
            f16x8 a = {};
            if (tap < 27 && m < OC) {
#pragma unroll
                for (int j = 0; j < 8; ++j)
                    a[j] = (_Float16)wt[(size_t)m * 216 + (size_t)j * 27 + tap];
            }
            afr[mt][s] = a;
        }
    }

    int boff[7];
#pragma unroll
    for (int s = 0; s < 7; ++s) {
        int tap = s * 4 + quad;
        if (tap > 26) tap = 26;            // A is zero there
        const int kd = tap / 9, kh = (tap % 9) / 3, kw = tap % 3;
        boff[s] = (wid + kd) * (6 * 66) + kh * 66 + kw + n;
    }

    float bv[MT][4];
#pragma unroll
    for (int mt = 0; mt < MT; ++mt)
#pragma unroll
        for (int r = 0; r < 4; ++r) {
            const int o = mt * 16 + quad * 4 + r;
            bv[mt][r] = ((OM != 1) && bias != nullptr && o < OC) ? bias[o] : 0.f;
        }

    __syncthreads();

    const size_t outbase = (size_t)(d0 + wid) * HW + (size_t)h0 * WW + w0;

#pragma unroll 1
    for (int nt = 0; nt < 16; ++nt) {      // 16 n-tiles of 16 voxels per wave
        const int hl = nt >> 2, wseg = nt & 3;
        const int add = hl * 66 + wseg * 16;
        f32x4 acc[MT];
#pragma unroll
        for (int mt = 0; mt < MT; ++mt) {
            acc[mt][0] = bv[mt][0]; acc[mt][1] = bv[mt][1];
            acc[mt][2] = bv[mt][2]; acc[mt][3] = bv[mt][3];
        }
#pragma unroll
        for (int s = 0; s < 7; ++s) {
            const f16x8 b = hal[boff[s] + add];
            acc[0] = __builtin_amdgcn_mfma_f32_16x16x32_f16(afr[0][s], b, acc[0], 0, 0, 0);
            if (MT > 1)
                acc[1] = __builtin_amdgcn_mfma_f32_16x16x32_f16(afr[1][s], b, acc[1], 0, 0, 0);
        }
        const size_t vox = outbase + (size_t)hl * WW + wseg * 16 + n;

        if (OM == 0) {
            // interleaved 8-ch: lane(quad<2) holds channels quad*4+r
            if (quad < 2) {
                f16x4 o4;
#pragma unroll
                for (int r = 0; r < 4; ++r) {
                    float v = acc[0][r];
                    if (RELU) v = fmaxf(v, 0.f);
                    o4[r] = (_Float16)v;
                }
                *(f16x4*)((_Float16*)out + vox * 8 + quad * 4) = o4;
            }
        } else if (OM == 1) {
            float ssum = 0.f;
#pragma unroll
            for (int mt = 0; mt < MT; ++mt)
#pragma unroll
                for (int r = 0; r < 4; ++r) ssum += fabsf(acc[mt][r]);
            ssum += __shfl_xor(ssum, 16);
            ssum += __shfl_xor(ssum, 32);
            const float inv = 1.0f / fmaxf(ssum, 1e-12f);
#pragma unroll
            for (int mt = 0; mt < MT; ++mt)
#pragma unroll
                for (int r = 0; r < 4; ++r) {
                    const int o = mt * 16 + quad * 4 + r;
                    if (o < OC) stv((TO*)out + (size_t)o * VOL + vox, acc[mt][r] * inv);
                }
        } else { // OM == 2, OC = 1 planar
            if (quad == 0) {
                float v = acc[0][0];
                if (RELU) v = fmaxf(v, 0.f);
                stv((TO*)out + vox, v);
            }
        }
    }
}

// ==========================================================================
// adapt8: per-voxel 27-tap weights, 8 interleaved channels.
// Thread = 1 voxel: 27 coalesced f16x8 neighbor loads + 27 coalesced 2B
// weight loads, all independent; fp32 accumulate via v_fma_mix.
// ==========================================================================
__global__ __launch_bounds__(256) void adapt8(const _Float16* __restrict__ in,
                                              const _Float16* __restrict__ wn,
                                              _Float16* __restrict__ out)
{
    const int tid = threadIdx.x;
    const int bid = blockIdx.x;            // 8192 = 128 d x 64 h-pairs
    const int d = bid >> 6;
    const int h = ((bid & 63) << 1) + (tid >> 7);
    const int w = tid & 127;
    const size_t vox = (size_t)d * HW + (size_t)h * WW + w;

    _Float16 wk[27];
#pragma unroll
    for (int k = 0; k < 27; ++k) wk[k] = wn[(size_t)k * VOL + vox];

    float acc[8] = {0.f, 0.f, 0.f, 0.f, 0.f, 0.f, 0.f, 0.f};
#pragma unroll
    for (int kd = 0; kd < 3; ++kd) {
        const int gd = d + kd - 1;
#pragma unroll
        for (int kh = 0; kh < 3; ++kh) {
            const int gh = h + kh - 1;
#pragma unroll
            for (int kw = 0; kw < 3; ++kw) {
                const int gw = w + kw - 1;
                const bool ok = ((unsigned)gd < (unsigned)DD) &&
                                ((unsigned)gh < (unsigned)HH) &&
                                ((unsigned)gw < (unsigned)WW);
                f16x8 xv = {};
                if (ok)
                    xv = *(const f16x8*)(in + ((size_t)gd * HW + (size_t)gh * WW + gw) * 8);
                const float wv = (float)wk[kd * 9 + kh * 3 + kw];
#pragma unroll
                for (int c = 0; c < 8; ++c) acc[c] += wv * (float)xv[c];
            }
        }
    }
    f16x8 o;
#pragma unroll
    for (int c = 0; c < 8; ++c) o[c] = (_Float16)acc[c];
    *(f16x8*)(out + vox * 8) = o;
}

// ==========================================================================
// adapt1: 1 channel, planar in/out. Thread = 4 consecutive w voxels.
// ==========================================================================
template <typename TOUT>
__global__ __launch_bounds__(256) void adapt1(const _Float16* __restrict__ in,
                                              const _Float16* __restrict__ wn,
                                              TOUT* __restrict__ out)
{
    const int tid = threadIdx.x;
    const int wg  = tid & 31;              // 32 w-groups of 4
    const int hl  = tid >> 5;              // 0..7
    const int bid = blockIdx.x;            // 2048 = 128 d * 16 h-blocks
    const int d   = bid >> 4;
    const int h   = ((bid & 15) << 3) + hl;
    const int w0  = wg << 2;
    const size_t base = (size_t)d * HW + (size_t)h * WW + w0;

    f16x4 wk[27];
#pragma unroll
    for (int k = 0; k < 27; ++k)
        wk[k] = *(const f16x4*)(wn + (size_t)k * VOL + base);

    float acc[4] = {0.f, 0.f, 0.f, 0.f};
#pragma unroll
    for (int kd = 0; kd < 3; ++kd) {
        const int gd = d + kd - 1;
#pragma unroll
        for (int kh = 0; kh < 3; ++kh) {
            const int gh = h + kh - 1;
            const bool rowok = ((unsigned)gd < (unsigned)DD) &&
                               ((unsigned)gh < (unsigned)HH);
            const _Float16* rp = in + (size_t)gd * HW + (size_t)gh * WW;
            float xv[6];
            if (rowok) {
                f16x4 cen = *(const f16x4*)(rp + w0);
                xv[1] = (float)cen[0]; xv[2] = (float)cen[1];
                xv[3] = (float)cen[2]; xv[4] = (float)cen[3];
                xv[0] = (w0 > 0)   ? (float)rp[w0 - 1] : 0.f;
                xv[5] = (w0 < 124) ? (float)rp[w0 + 4] : 0.f;
            } else {
#pragma unroll
                for (int j = 0; j < 6; ++j) xv[j] = 0.f;
            }
            const int kb = kd * 9 + kh * 3;
#pragma unroll
            for (int kw = 0; kw < 3; ++kw) {
                const f16x4 w4 = wk[kb + kw];
                acc[0] += (float)w4[0] * xv[kw + 0];
                acc[1] += (float)w4[1] * xv[kw + 1];
                acc[2] += (float)w4[2] * xv[kw + 2];
                acc[3] += (float)w4[3] * xv[kw + 3];
            }
        }
    }
    typedef TOUT tout4 __attribute__((ext_vector_type(4)));
    tout4 o4;
    o4[0] = (TOUT)acc[0]; o4[1] = (TOUT)acc[1];
    o4[2] = (TOUT)acc[2]; o4[3] = (TOUT)acc[3];
    *(tout4*)(out + base) = o4;
}

extern "C" void kernel_launch(void* const* d_in, const int* in_sizes, int n_in,
                              void* d_out, int out_size, void* d_ws, size_t ws_size,
                              hipStream_t stream)
{
    (void)in_sizes; (void)n_in; (void)out_size; (void)ws_size;

    const float* x      = (const float*)d_in[0];
    const float* ac1_w1 = (const float*)d_in[1];
    const float* ac1_b1 = (const float*)d_in[2];
    const float* ac1_w2 = (const float*)d_in[3];
    const float* ac2_w1 = (const float*)d_in[4];
    const float* ac2_b1 = (const float*)d_in[5];
    const float* ac2_w2 = (const float*)d_in[6];
    const float* ac3_w1 = (const float*)d_in[7];
    const float* ac3_b1 = (const float*)d_in[8];
    const float* ac3_w2 = (const float*)d_in[9];
    const float* mid_w  = (const float*)d_in[10];
    const float* mid_b  = (const float*)d_in[11];
    const float* out_w  = (const float*)d_in[12];
    const float* out_b  = (const float*)d_in[13];
    float* outp = (float*)d_out;

    // fp16 scratch (172 MB total, same footprint as the R3 run that passed):
    // Wb = 27V planar weight field | B1i = 8V interleaved | B2i = 8V interleaved
    const size_t V = (size_t)VOL;
    _Float16* Wb  = (_Float16*)d_ws;
    _Float16* B1i = Wb + 27 * V;
    _Float16* B2i = B1i + 8 * V;
    _Float16* F0  = B2i;        // block-3 planar 1-ch ping-pong (B2 free there)
    _Float16* F1  = B2i + V;

    const dim3 cgrid(2048), cblk(256);
    const dim3 a8grid(8192), a8blk(256);
    const dim3 a1grid(2048), a1blk(256);

    cvt_x<<<8192, 256, 0, stream>>>(x, B2i);                                    // B2i = x (interleaved)

    // ---- adaptive block 1 (input x = B2i) ----
    conv_mfma<8, true, 0, _Float16><<<cgrid, cblk, 0, stream>>>(B2i, ac1_w1, ac1_b1, B1i);
    conv_mfma<27, false, 1, _Float16><<<cgrid, cblk, 0, stream>>>(B1i, ac1_w2, nullptr, Wb);
    adapt8<<<a8grid, a8blk, 0, stream>>>(B2i, Wb, B1i);
    adapt8<<<a8grid, a8blk, 0, stream>>>(B1i, Wb, B2i);
    adapt8<<<a8grid, a8blk, 0, stream>>>(B2i, Wb, B1i);                         // B1i = block1 out
    conv_mfma<8, false, 0, _Float16><<<cgrid, cblk, 0, stream>>>(B1i, mid_w, mid_b, B2i); // B2i = mid

    // ---- adaptive block 2 (input mid = B2i) ----
    conv_mfma<8, true, 0, _Float16><<<cgrid, cblk, 0, stream>>>(B2i, ac2_w1, ac2_b1, B1i);
    conv_mfma<27, false, 1, _Float16><<<cgrid, cblk, 0, stream>>>(B1i, ac2_w2, nullptr, Wb);
    adapt8<<<a8grid, a8blk, 0, stream>>>(B2i, Wb, B1i);
    adapt8<<<a8grid, a8blk, 0, stream>>>(B1i, Wb, B2i);
    adapt8<<<a8grid, a8blk, 0, stream>>>(B2i, Wb, B1i);                         // B1i = mid2

    // ---- block 3: weights from mid2 = B1i ----
    conv_mfma<8, true, 0, _Float16><<<cgrid, cblk, 0, stream>>>(B1i, ac3_w1, ac3_b1, B2i);
    conv_mfma<27, false, 1, _Float16><<<cgrid, cblk, 0, stream>>>(B2i, ac3_w2, nullptr, Wb);
    conv_mfma<1, false, 2, _Float16><<<cgrid, cblk, 0, stream>>>(B1i, out_w, out_b, F0);
    adapt1<_Float16><<<a1grid, a1blk, 0, stream>>>(F0, Wb, F1);
    adapt1<_Float16><<<a1grid, a1blk, 0, stream>>>(F1, Wb, F0);
    adapt1<float><<<a1grid, a1blk, 0, stream>>>(F0, Wb, outp);
}

// Round 6
// 1006.607 us; speedup vs baseline: 8.5194x; 1.0313x over previous
//
#include <hip/hip_runtime.h>
#include <hip/hip_fp16.h>
#include <math.h>

#define WW 128
#define HH 128
#define DD 128
#define HW (WW * HH)
#define VOL (WW * HH * DD)
#define WSTRIDE 32   // weight-field taps stride: [vox][32] fp16, taps 0..26 used

typedef _Float16 f16x8 __attribute__((ext_vector_type(8)));
typedef _Float16 f16x4 __attribute__((ext_vector_type(4)));
typedef _Float16 f16x2 __attribute__((ext_vector_type(2)));
typedef float f32x4 __attribute__((ext_vector_type(4)));
typedef int int4v __attribute__((ext_vector_type(4)));

__device__ __forceinline__ float ldv(const float* p) { return *p; }
__device__ __forceinline__ float ldv(const _Float16* p) { return (float)*p; }
__device__ __forceinline__ void stv(float* p, float v) { *p = v; }
__device__ __forceinline__ void stv(_Float16* p, float v) { *p = (_Float16)v; }

// ==========================================================================
// cvt_x: planar fp32 (8ch) -> channel-interleaved f16x8 [d][h][w][c8]
// ==========================================================================
__global__ __launch_bounds__(256) void cvt_x(const float* __restrict__ x,
                                             _Float16* __restrict__ xi)
{
    const size_t v = (size_t)blockIdx.x * 256 + threadIdx.x;
    f16x8 o;
#pragma unroll
    for (int c = 0; c < 8; ++c) o[c] = (_Float16)x[(size_t)c * VOL + v];
    *(f16x8*)(xi + v * 8) = o;
}

// ==========================================================================
// Implicit-GEMM 3x3x3 conv via MFMA f16, input channel-interleaved f16x8.
//   D[OC, vox] = W[OC, K=216] * im2col[K, vox], K order k = tap*8 + c.
// Block tile 4d x 4h x 64w; halo 6x6x66 sites, ONE f16x8 load per site.
// OM: 0 = interleaved 8-ch out
//     1 = L1-normalized 27-tap weight field, layout [vox][32] fp16
//         (bpermute transpose -> one dwordx4 store per lane per nt)
//     2 = planar 1-ch out
// ==========================================================================
template <int OC, bool RELU, int OM, typename TO>
__global__ __launch_bounds__(256) void conv_mfma(const _Float16* __restrict__ in,
                                                 const float* __restrict__ wt,
                                                 const float* __restrict__ bias,
                                                 TO* __restrict__ out)
{
    __shared__ f16x8 hal[6 * 6 * 66];

    const int bid  = blockIdx.x;           // 2048 blocks: 32d x 32h x 2w
    const int wblk = bid & 1;
    const int hblk = (bid >> 1) & 31;
    const int dblk = bid >> 6;
    const int d0 = dblk * 4, h0 = hblk * 4, w0 = wblk * 64;

    const int tid = threadIdx.x;
    for (int s = tid; s < 6 * 6 * 66; s += 256) {
        const int dd = s / (6 * 66);
        const int r  = s % (6 * 66);
        const int hh = r / 66;
        const int ww = r % 66;
        const int gd = d0 + dd - 1, gh = h0 + hh - 1, gw = w0 + ww - 1;
        f16x8 v = {};
        if ((unsigned)gd < (unsigned)DD && (unsigned)gh < (unsigned)HH &&
            (unsigned)gw < (unsigned)WW)
            v = *(const f16x8*)(in + ((size_t)gd * HW + (size_t)gh * WW + gw) * 8);
        hal[s] = v;
    }

    const int lane = tid & 63;
    const int wid  = tid >> 6;             // wave id = local d slice
    const int n    = lane & 15;
    const int quad = lane >> 4;

    // ---- A fragments: weights resident in VGPRs ----
    constexpr int MT = (OC > 16) ? 2 : 1;
    f16x8 afr[MT][7];
#pragma unroll
    for (int s = 0; s < 7; ++s) {
        const int tap = s * 4 + quad;      // k = tap*8 + c
#pragma unroll
        for (int mt = 0; mt < MT; ++mt) {
            const int m = mt * 16 + n;
            f16x8 a = {};
            if (tap < 27 && m < OC) {
#pragma unroll
                for (int j = 0; j < 8; ++j)
                    a[j] = (_Float16)wt[(size_t)m * 216 + (size_t)j * 27 + tap];
            }
            afr[mt][s] = a;
        }
    }

    int boff[7];
#pragma unroll
    for (int s = 0; s < 7; ++s) {
        int tap = s * 4 + quad;
        if (tap > 26) tap = 26;            // A is zero there
        const int kd = tap / 9, kh = (tap % 9) / 3, kw = tap % 3;
        boff[s] = (wid + kd) * (6 * 66) + kh * 66 + kw + n;
    }

    float bv[MT][4];
#pragma unroll
    for (int mt = 0; mt < MT; ++mt)
#pragma unroll
        for (int r = 0; r < 4; ++r) {
            const int o = mt * 16 + quad * 4 + r;
            bv[mt][r] = ((OM != 1) && bias != nullptr && o < OC) ? bias[o] : 0.f;
        }

    __syncthreads();

    const size_t outbase = (size_t)(d0 + wid) * HW + (size_t)h0 * WW + w0;

#pragma unroll 1
    for (int nt = 0; nt < 16; ++nt) {      // 16 n-tiles of 16 voxels per wave
        const int hl = nt >> 2, wseg = nt & 3;
        const int add = hl * 66 + wseg * 16;
        f32x4 acc[MT];
#pragma unroll
        for (int mt = 0; mt < MT; ++mt) {
            acc[mt][0] = bv[mt][0]; acc[mt][1] = bv[mt][1];
            acc[mt][2] = bv[mt][2]; acc[mt][3] = bv[mt][3];
        }
#pragma unroll
        for (int s = 0; s < 7; ++s) {
            const f16x8 b = hal[boff[s] + add];
            acc[0] = __builtin_amdgcn_mfma_f32_16x16x32_f16(afr[0][s], b, acc[0], 0, 0, 0);
            if (MT > 1)
                acc[1] = __builtin_amdgcn_mfma_f32_16x16x32_f16(afr[1][s], b, acc[1], 0, 0, 0);
        }
        const size_t vox = outbase + (size_t)hl * WW + wseg * 16 + n;

        if (OM == 0) {
            // interleaved 8-ch: lanes with quad<2 hold channels quad*4+r
            if (quad < 2) {
                f16x4 o4;
#pragma unroll
                for (int r = 0; r < 4; ++r) {
                    float v = acc[0][r];
                    if (RELU) v = fmaxf(v, 0.f);
                    o4[r] = (_Float16)v;
                }
                *(f16x4*)((_Float16*)out + vox * 8 + quad * 4) = o4;
            }
        } else if (OM == 1) {
            // ---- L1 norm across the 4-lane voxel group ----
            float ssum = 0.f;
#pragma unroll
            for (int mt = 0; mt < MT; ++mt)
#pragma unroll
                for (int r = 0; r < 4; ++r) ssum += fabsf(acc[mt][r]);
            ssum += __shfl_xor(ssum, 16);
            ssum += __shfl_xor(ssum, 32);
            const float inv = 1.0f / fmaxf(ssum, 1e-12f);
            // ---- pack scaled values to f16x2 words: p[mt][rr] = (r=2rr, 2rr+1)
            int p[2][2];
#pragma unroll
            for (int mt = 0; mt < MT; ++mt)
#pragma unroll
                for (int rr = 0; rr < 2; ++rr) {
                    f16x2 t;
                    t[0] = (_Float16)(acc[mt][2 * rr] * inv);
                    t[1] = (_Float16)(acc[mt][2 * rr + 1] * inv);
                    p[mt][rr] = __builtin_bit_cast(int, t);
                }
            // ---- bpermute transpose: lane (quad,n) gathers taps 8q..8q+7 of vox n
            int4v wv;
#pragma unroll
            for (int w = 0; w < 4; ++w) {
                const int sq = (2 * quad + (w >> 1)) & 3;
                const int bidx = ((sq << 4) | n) << 2;
                const int a0 = __builtin_amdgcn_ds_bpermute(bidx, p[0][w & 1]);
                const int a1 = __builtin_amdgcn_ds_bpermute(bidx, p[1][w & 1]);
                wv[w] = (quad < 2) ? a0 : a1;
            }
            *(int4v*)((_Float16*)out + (vox << 5) + (quad << 3)) = wv;
        } else { // OM == 2, OC = 1 planar
            if (quad == 0) {
                float v = acc[0][0];
                if (RELU) v = fmaxf(v, 0.f);
                stv((TO*)out + vox, v);
            }
        }
    }
}

// ==========================================================================
// adapt8: per-voxel 27-tap weights [vox][32] fp16, 8 interleaved channels.
// Thread = 1 voxel: 4 f16x8 weight loads + 27 f16x8 neighbor loads,
// fp32 accumulate via v_fma_mix.
// ==========================================================================
__global__ __launch_bounds__(256) void adapt8(const _Float16* __restrict__ in,
                                              const _Float16* __restrict__ wn,
                                              _Float16* __restrict__ out)
{
    const int tid = threadIdx.x;
    const int bid = blockIdx.x;            // 8192 = 128 d x 64 h-pairs
    const int d = bid >> 6;
    const int h = ((bid & 63) << 1) + (tid >> 7);
    const int w = tid & 127;
    const size_t vox = (size_t)d * HW + (size_t)h * WW + w;

    const f16x8* wrow = (const f16x8*)(wn + (vox << 5));
    f16x8 wkv[4];
#pragma unroll
    for (int j = 0; j < 4; ++j) wkv[j] = wrow[j];

    float acc[8] = {0.f, 0.f, 0.f, 0.f, 0.f, 0.f, 0.f, 0.f};
#pragma unroll
    for (int kd = 0; kd < 3; ++kd) {
        const int gd = d + kd - 1;
#pragma unroll
        for (int kh = 0; kh < 3; ++kh) {
            const int gh = h + kh - 1;
#pragma unroll
            for (int kw = 0; kw < 3; ++kw) {
                const int gw = w + kw - 1;
                const bool ok = ((unsigned)gd < (unsigned)DD) &&
                                ((unsigned)gh < (unsigned)HH) &&
                                ((unsigned)gw < (unsigned)WW);
                f16x8 xv = {};
                if (ok)
                    xv = *(const f16x8*)(in + ((size_t)gd * HW + (size_t)gh * WW + gw) * 8);
                const int t = kd * 9 + kh * 3 + kw;
                const float wvv = (float)wkv[t >> 3][t & 7];
#pragma unroll
                for (int c = 0; c < 8; ++c) acc[c] += wvv * (float)xv[c];
            }
        }
    }
    f16x8 o;
#pragma unroll
    for (int c = 0; c < 8; ++c) o[c] = (_Float16)acc[c];
    *(f16x8*)(out + vox * 8) = o;
}

// ==========================================================================
// adapt1: 1 channel, planar in/out; weights [vox][32]. Thread = 1 voxel.
// ==========================================================================
template <typename TOUT>
__global__ __launch_bounds__(256) void adapt1(const _Float16* __restrict__ in,
                                              const _Float16* __restrict__ wn,
                                              TOUT* __restrict__ out)
{
    const size_t vox = (size_t)blockIdx.x * 256 + threadIdx.x;
    const int w = (int)(vox & 127);
    const int h = (int)((vox >> 7) & 127);
    const int d = (int)(vox >> 14);

    const f16x8* wrow = (const f16x8*)(wn + (vox << 5));
    f16x8 wkv[4];
#pragma unroll
    for (int j = 0; j < 4; ++j) wkv[j] = wrow[j];

    float acc = 0.f;
#pragma unroll
    for (int kd = 0; kd < 3; ++kd) {
        const int gd = d + kd - 1;
#pragma unroll
        for (int kh = 0; kh < 3; ++kh) {
            const int gh = h + kh - 1;
#pragma unroll
            for (int kw = 0; kw < 3; ++kw) {
                const int gw = w + kw - 1;
                const bool ok = ((unsigned)gd < (unsigned)DD) &&
                                ((unsigned)gh < (unsigned)HH) &&
                                ((unsigned)gw < (unsigned)WW);
                float xv = 0.f;
                if (ok)
                    xv = (float)in[(size_t)gd * HW + (size_t)gh * WW + gw];
                const int t = kd * 9 + kh * 3 + kw;
                acc += (float)wkv[t >> 3][t & 7] * xv;
            }
        }
    }
    stv(out + vox, acc);
}

extern "C" void kernel_launch(void* const* d_in, const int* in_sizes, int n_in,
                              void* d_out, int out_size, void* d_ws, size_t ws_size,
                              hipStream_t stream)
{
    (void)in_sizes; (void)n_in; (void)out_size; (void)ws_size;

    const float* x      = (const float*)d_in[0];
    const float* ac1_w1 = (const float*)d_in[1];
    const float* ac1_b1 = (const float*)d_in[2];
    const float* ac1_w2 = (const float*)d_in[3];
    const float* ac2_w1 = (const float*)d_in[4];
    const float* ac2_b1 = (const float*)d_in[5];
    const float* ac2_w2 = (const float*)d_in[6];
    const float* ac3_w1 = (const float*)d_in[7];
    const float* ac3_b1 = (const float*)d_in[8];
    const float* ac3_w2 = (const float*)d_in[9];
    const float* mid_w  = (const float*)d_in[10];
    const float* mid_b  = (const float*)d_in[11];
    const float* out_w  = (const float*)d_in[12];
    const float* out_b  = (const float*)d_in[13];
    float* outp = (float*)d_out;

    // fp16 scratch, 192 MB total (ws is >=236 MB per R2 forensics):
    // Wb = [vox][32] weight field (32V) | B1i = 8V interleaved | B2i = 8V interleaved
    const size_t V = (size_t)VOL;
    _Float16* Wb  = (_Float16*)d_ws;
    _Float16* B1i = Wb + 32 * V;
    _Float16* B2i = B1i + 8 * V;
    _Float16* F0  = B2i;        // block-3 planar 1-ch ping-pong (B2i free there)
    _Float16* F1  = B2i + V;

    const dim3 cgrid(2048), cblk(256);
    const dim3 a8grid(8192), a8blk(256);
    const dim3 a1grid(8192), a1blk(256);

    cvt_x<<<8192, 256, 0, stream>>>(x, B2i);                                    // B2i = x (interleaved)

    // ---- adaptive block 1 (input x = B2i) ----
    conv_mfma<8, true, 0, _Float16><<<cgrid, cblk, 0, stream>>>(B2i, ac1_w1, ac1_b1, B1i);
    conv_mfma<27, false, 1, _Float16><<<cgrid, cblk, 0, stream>>>(B1i, ac1_w2, nullptr, Wb);
    adapt8<<<a8grid, a8blk, 0, stream>>>(B2i, Wb, B1i);
    adapt8<<<a8grid, a8blk, 0, stream>>>(B1i, Wb, B2i);
    adapt8<<<a8grid, a8blk, 0, stream>>>(B2i, Wb, B1i);                         // B1i = block1 out
    conv_mfma<8, false, 0, _Float16><<<cgrid, cblk, 0, stream>>>(B1i, mid_w, mid_b, B2i); // B2i = mid

    // ---- adaptive block 2 (input mid = B2i) ----
    conv_mfma<8, true, 0, _Float16><<<cgrid, cblk, 0, stream>>>(B2i, ac2_w1, ac2_b1, B1i);
    conv_mfma<27, false, 1, _Float16><<<cgrid, cblk, 0, stream>>>(B1i, ac2_w2, nullptr, Wb);
    adapt8<<<a8grid, a8blk, 0, stream>>>(B2i, Wb, B1i);
    adapt8<<<a8grid, a8blk, 0, stream>>>(B1i, Wb, B2i);
    adapt8<<<a8grid, a8blk, 0, stream>>>(B2i, Wb, B1i);                         // B1i = mid2

    // ---- block 3: weights from mid2 = B1i ----
    conv_mfma<8, true, 0, _Float16><<<cgrid, cblk, 0, stream>>>(B1i, ac3_w1, ac3_b1, B2i);
    conv_mfma<27, false, 1, _Float16><<<cgrid, cblk, 0, stream>>>(B2i, ac3_w2, nullptr, Wb);
    conv_mfma<1, false, 2, _Float16><<<cgrid, cblk, 0, stream>>>(B1i, out_w, out_b, F0);
    adapt1<_Float16><<<a1grid, a1blk, 0, stream>>>(F0, Wb, F1);
    adapt1<_Float16><<<a1grid, a1blk, 0, stream>>>(F1, Wb, F0);
    adapt1<float><<<a1grid, a1blk, 0, stream>>>(F0, Wb, outp);
}